// Round 1
// baseline (579.557 us; speedup 1.0000x reference)
//
#include <hip/hip_runtime.h>
#include <math.h>

#define VOCAB 400000
#define D 300
#define NF 256
#define TOPK 5
#define NS 200
#define LS 64
#define LQ 30
#define RS (NS*LS)      /* 12800 sentence rows */
#define RT (RS+LQ)      /* 12830 real rows (sents then question) */
#define MP 12832        /* rows padded to 32 (2 zero rows after question) */
#define KQ 320          /* padded emb dim for MFMA (300 -> 320) */
#define KC3 960         /* conv GEMM K = 3*320 */

/* ws layout (float offsets). bf16 regions counted as elems/2 floats. */
#define F_ROWS16 0                          /* ushort[MP*320]  */
#define F_FILT16 (F_ROWS16 + (MP*KQ/2))    /* ushort[256*960] */
#define F_CONV16 (F_FILT16 + (NF*KC3/2))   /* ushort[MP*256]  */
#define F_NE     (F_CONV16 + (MP*NF/2))
#define F_NC     (F_NE + RT)
#define F_MK     (F_NC + RT)
#define F_SENT   (F_MK + RT)

typedef __attribute__((ext_vector_type(8))) short bf16x8;
typedef __attribute__((ext_vector_type(4))) float f32x4;

__device__ inline ushort f2bf(float f) {
    union { float f; unsigned u; } x; x.f = f;
    unsigned r = x.u + 0x7fffu + ((x.u >> 16) & 1u);   /* RNE */
    return (ushort)(r >> 16);
}
__device__ inline float bf2f(ushort h) {
    union { unsigned u; float f; } x; x.u = ((unsigned)h) << 16; return x.f;
}

/* order-preserving bijection f32 -> u32 (unsigned compare == float compare) */
__device__ inline unsigned f2key(float f) {
    unsigned u = __float_as_uint(f);
    return (u & 0x80000000u) ? ~u : (u | 0x80000000u);
}
__device__ inline float key2f(unsigned k) {
    unsigned u = (k & 0x80000000u) ? (k & 0x7fffffffu) : ~k;
    return __uint_as_float(u);
}

/* ---- Kernel 1: gather rows -> bf16 [MP][320], emb norms, mask ----
   4 rows per block (4 waves). */
__global__ __launch_bounds__(256)
void gather16_kernel(const float* __restrict__ emb,
                     const int* __restrict__ question,
                     const int* __restrict__ sents,
                     float* __restrict__ ws) {
    int w = threadIdx.x >> 6, lane = threadIdx.x & 63;
    int r = blockIdx.x * 4 + w;      /* 0..MP-1 */
    ushort* rows16 = (ushort*)(ws + F_ROWS16) + (size_t)r * KQ;
    if (r >= RT) {                   /* zero pad rows */
        #pragma unroll
        for (int i = 0; i < 5; ++i) rows16[lane + i*64] = 0;
        return;
    }
    int idx = (r < RS) ? sents[r] : question[r - RS];
    const float* src = emb + (size_t)idx * D;
    float ss = 0.f;
    #pragma unroll
    for (int i = 0; i < 5; ++i) {
        int d = lane + i*64;
        float v = (d < D) ? src[d] : 0.f;
        rows16[d] = f2bf(v);
        ss += v*v;
    }
    #pragma unroll
    for (int off = 32; off; off >>= 1) ss += __shfl_xor(ss, off, 64);
    if (lane == 0) {
        ws[F_NE + r] = sqrtf(ss);
        ws[F_MK + r] = (idx > 1) ? 1.f : 0.f;
    }
}

/* ---- Kernel 2: filters -> bf16 [256][960] (3 segs of 320, zero-padded) ---- */
__global__ void filt16_kernel(const float* __restrict__ filt, float* __restrict__ ws) {
    int f = blockIdx.x, lane = threadIdx.x;
    ushort* dst = (ushort*)(ws + F_FILT16) + (size_t)f * KC3;
    #pragma unroll
    for (int seg = 0; seg < 3; ++seg)
        #pragma unroll
        for (int i = 0; i < 5; ++i) {
            int d = lane + i*64;
            float v = (d < D) ? filt[f*900 + seg*300 + d] : 0.f;
            dst[seg*KQ + d] = f2bf(v);
        }
}

/* ---- Kernel 3: conv as bf16 MFMA GEMM, staged with shift (no im2col) ----
   out[r][f] = sum_seg [valid] sum_d rows[r+seg][d]*filt[f][seg][d]
   Tile 64x64, 4 waves each 32x32, BK=64 (2 MFMA k-chunks). */
__global__ __launch_bounds__(256)
void conv16_gemm_kernel(const float* __restrict__ ws_c, float* __restrict__ ws) {
    __shared__ ushort As[64*72];
    __shared__ ushort Bs[64*72];
    const ushort* rows16 = (const ushort*)(ws_c + F_ROWS16);
    const ushort* filt16 = (const ushort*)(ws_c + F_FILT16);
    ushort* conv16 = (ushort*)(ws + F_CONV16);
    int m0 = blockIdx.x * 64;
    int f0 = blockIdx.y * 64;
    int tid = threadIdx.x;
    int lane = tid & 63, w = tid >> 6;
    int srow = tid >> 3, sh = tid & 7;
    int qm = (w & 1) * 32, fn = (w >> 1) * 32;

    f32x4 acc00 = {}, acc01 = {}, acc10 = {}, acc11 = {};

    for (int kt = 0; kt < 15; ++kt) {
        int seg = kt / 5;
        int dbase = (kt % 5) * 64;
        #pragma unroll
        for (int p = 0; p < 2; ++p) {
            int row = p*32 + srow;
            int gr = m0 + row;
            bool ok = (gr < RS) ? (((gr & 63) + seg) < LS) : ((gr + seg) < RT);
            uint4 val = make_uint4(0,0,0,0);
            if (ok) val = *(const uint4*)(rows16 + (size_t)(gr + seg)*KQ + dbase + sh*8);
            *(uint4*)&As[row*72 + sh*8] = val;
            int col = p*32 + srow;
            uint4 bv = *(const uint4*)(filt16 + (size_t)(f0 + col)*KC3 + kt*64 + sh*8);
            *(uint4*)&Bs[col*72 + sh*8] = bv;
        }
        __syncthreads();
        #pragma unroll
        for (int kc = 0; kc < 2; ++kc) {
            int ko = kc*32 + (lane >> 4)*8;
            bf16x8 a0 = *(const bf16x8*)&As[(qm + (lane & 15))*72 + ko];
            bf16x8 a1 = *(const bf16x8*)&As[(qm + 16 + (lane & 15))*72 + ko];
            bf16x8 b0 = *(const bf16x8*)&Bs[(fn + (lane & 15))*72 + ko];
            bf16x8 b1 = *(const bf16x8*)&Bs[(fn + 16 + (lane & 15))*72 + ko];
            acc00 = __builtin_amdgcn_mfma_f32_16x16x32_bf16(a0, b0, acc00, 0, 0, 0);
            acc01 = __builtin_amdgcn_mfma_f32_16x16x32_bf16(a0, b1, acc01, 0, 0, 0);
            acc10 = __builtin_amdgcn_mfma_f32_16x16x32_bf16(a1, b0, acc10, 0, 0, 0);
            acc11 = __builtin_amdgcn_mfma_f32_16x16x32_bf16(a1, b1, acc11, 0, 0, 0);
        }
        __syncthreads();
    }
    int mb = m0 + qm + (lane >> 4) * 4;
    int fb = f0 + fn + (lane & 15);
    #pragma unroll
    for (int r = 0; r < 4; ++r) {
        int r0 = mb + r;
        if (r0 < MP) {
            conv16[(size_t)r0*NF + fb]        = f2bf(acc00[r]);
            conv16[(size_t)r0*NF + fb + 16]   = f2bf(acc01[r]);
        }
        int r1 = mb + 16 + r;
        if (r1 < MP) {
            conv16[(size_t)r1*NF + fb]        = f2bf(acc10[r]);
            conv16[(size_t)r1*NF + fb + 16]   = f2bf(acc11[r]);
        }
    }
}

/* ---- Kernel 4: conv row norms from bf16 conv ---- */
__global__ void convnorm16_kernel(float* __restrict__ ws) {
    const ushort* conv16 = (const ushort*)(ws + F_CONV16);
    int w = threadIdx.x >> 6, lane = threadIdx.x & 63;
    int r = blockIdx.x*4 + w;
    if (r >= RT) return;
    ushort4 v = *(const ushort4*)(conv16 + (size_t)r*NF + lane*4);
    float a = bf2f(v.x), b = bf2f(v.y), c = bf2f(v.z), d = bf2f(v.w);
    float ss = a*a + b*b + c*c + d*d;
    #pragma unroll
    for (int off = 32; off; off >>= 1) ss += __shfl_xor(ss, off, 64);
    if (lane == 0) ws[F_NC + r] = sqrtf(ss);
}

/* ---- top-5 pool over 64 lanes: single-shuffle key max + ballot tiebreak ---- */
__device__ inline void pool64(float v, float& mx, float& mean5) {
    unsigned key = f2key(v);
    float sum = 0.f;
    mx = 0.f;
    #pragma unroll
    for (int it = 0; it < TOPK; ++it) {
        unsigned mk = key;
        #pragma unroll
        for (int off = 32; off; off >>= 1) {
            unsigned o = (unsigned)__shfl_xor((int)mk, off, 64);
            mk = (o > mk) ? o : mk;
        }
        float fv = key2f(mk);
        if (it == 0) mx = fv;
        sum += fv;
        /* eliminate exactly one instance (lowest lane holding the max) */
        unsigned long long b = __ballot(key == mk);
        int victim = (int)__builtin_ctzll(b);
        if ((int)(threadIdx.x & 63) == victim) key = 0u;   /* below any real key */
    }
    mean5 = sum * (1.f/TOPK);
}

/* ---- Kernel 5: fused sims (MFMA -> LDS) + normalize + pool + sigmoid ----
   grid NS x 512 (8 waves). Sim phase: wave w computes q-tile (w&1)*16,
   s-tile (w>>2 grouping) as before. Pool phase: wave w handles q = it*8+w. */
__global__ __launch_bounds__(512)
void simpool_kernel(const float* __restrict__ ws_c,
                    const float* __restrict__ dsim,
                    const float* __restrict__ lin_w,
                    const float* __restrict__ lin_b,
                    float* __restrict__ ws,
                    float* __restrict__ out) {
    __shared__ float Di[32*64];
    __shared__ float Ds[32*64];
    __shared__ float sred[8];
    const ushort* rows16 = (const ushort*)(ws_c + F_ROWS16);
    const ushort* conv16 = (const ushort*)(ws_c + F_CONV16);
    int n = blockIdx.x;
    int tid = threadIdx.x;
    int lane = tid & 63, w = tid >> 6;
    int qb = (w & 1) * 16;          /* q-tile: 0 or 16 */
    int sb = (w >> 1) * 16;         /* s-tile: 0,16,32,48 */
    int m = lane & 15, h = lane >> 4;

    /* insens: Q rows at RS.., S rows at n*64.., stride 320 */
    {
        const ushort* Q = rows16 + (size_t)RS * KQ;
        const ushort* S = rows16 + (size_t)(n*LS) * KQ;
        f32x4 acc = {};
        #pragma unroll
        for (int kc = 0; kc < 10; ++kc) {
            int ko = kc*32 + h*8;
            bf16x8 a = *(const bf16x8*)(Q + (size_t)(qb + m)*KQ + ko);
            bf16x8 b = *(const bf16x8*)(S + (size_t)(sb + m)*KQ + ko);
            acc = __builtin_amdgcn_mfma_f32_16x16x32_bf16(a, b, acc, 0, 0, 0);
        }
        #pragma unroll
        for (int r = 0; r < 4; ++r)
            Di[(qb + h*4 + r)*64 + sb + m] = acc[r];
    }
    /* sens: conv rows, stride 256 */
    {
        const ushort* Q = conv16 + (size_t)RS * NF;
        const ushort* S = conv16 + (size_t)(n*LS) * NF;
        f32x4 acc = {};
        #pragma unroll
        for (int kc = 0; kc < 8; ++kc) {
            int ko = kc*32 + h*8;
            bf16x8 a = *(const bf16x8*)(Q + (size_t)(qb + m)*NF + ko);
            bf16x8 b = *(const bf16x8*)(S + (size_t)(sb + m)*NF + ko);
            acc = __builtin_amdgcn_mfma_f32_16x16x32_bf16(a, b, acc, 0, 0, 0);
        }
        #pragma unroll
        for (int r = 0; r < 4; ++r)
            Ds[(qb + h*4 + r)*64 + sb + m] = acc[r];
    }
    __syncthreads();

    /* pool phase */
    float nes = ws_c[F_NE + n*LS + lane];
    float ncs = ws_c[F_NC + n*LS + lane];
    float mks = ws_c[F_MK + n*LS + lane];
    float w0 = lin_w[0], w1 = lin_w[1], w2 = lin_w[2],
          w3 = lin_w[3], w4 = lin_w[4], w5 = lin_w[5], bb = lin_b[0];
    float wsum = 0.f;
    for (int it = 0; it < 4; ++it) {
        int q = it*8 + w;
        if (q < LQ) {
            float neq = ws_c[F_NE + RS + q];
            float ncq = ws_c[F_NC + RS + q];
            float mkq = ws_c[F_MK + RS + q];
            float si = Di[q*64 + lane] / (neq * nes) * (mks * mkq);
            float sc = Ds[q*64 + lane] / (ncq * ncs);
            float so = dsim[(size_t)(n*LS + lane)*LQ + q];
            float f0,f1,f2,f3,f4,f5;
            pool64(si, f0, f1);
            pool64(sc, f2, f3);
            pool64(so, f4, f5);
            if (lane == 0) {
                float z = bb + f0*w0 + f1*w1 + f2*w2 + f3*w3 + f4*w4 + f5*w5;
                wsum += 1.f / (1.f + expf(-z));
            }
        }
    }
    if (lane == 0) sred[w] = wsum;
    __syncthreads();
    if (tid == 0) {
        float s = 0.f;
        #pragma unroll
        for (int i = 0; i < 8; ++i) s += sred[i];
        s *= (1.f/LQ);
        out[1 + n] = s;
        ws[F_SENT + n] = s;
    }
}

/* ---- Kernel 6: doc mean ---- */
__global__ void final_kernel(const float* __restrict__ ws, float* __restrict__ out) {
    __shared__ float red[256];
    int tid = threadIdx.x;
    red[tid] = (tid < NS) ? ws[F_SENT + tid] : 0.f;
    __syncthreads();
    for (int off = 128; off; off >>= 1) {
        if (tid < off) red[tid] += red[tid + off];
        __syncthreads();
    }
    if (tid == 0) out[0] = red[0] * (1.f/NS);
}

extern "C" void kernel_launch(void* const* d_in, const int* in_sizes, int n_in,
                              void* d_out, int out_size, void* d_ws, size_t ws_size,
                              hipStream_t stream) {
    const float* emb      = (const float*)d_in[0];
    const float* filt     = (const float*)d_in[1];
    const float* lin_w    = (const float*)d_in[2];
    const float* lin_b    = (const float*)d_in[3];
    const int*   question = (const int*)d_in[4];
    const int*   sents    = (const int*)d_in[5];
    const float* dsim     = (const float*)d_in[6];
    float* ws  = (float*)d_ws;
    float* out = (float*)d_out;

    gather16_kernel<<<MP/4, 256, 0, stream>>>(emb, question, sents, ws);
    filt16_kernel<<<NF, 64, 0, stream>>>(filt, ws);
    conv16_gemm_kernel<<<dim3(201, 4), 256, 0, stream>>>(ws, ws);
    convnorm16_kernel<<<(RT + 3)/4, 256, 0, stream>>>(ws);
    simpool_kernel<<<NS, 512, 0, stream>>>(ws, dsim, lin_w, lin_b, ws, out);
    final_kernel<<<1, 256, 0, stream>>>(ws, out);
}